// Round 3
// baseline (105.712 us; speedup 1.0000x reference)
//
#include <hip/hip_runtime.h>

#define D_  160
#define H_  192
#define W_  224
#define HW_ (H_ * W_)           // 43008
#define N_  (D_ * H_ * W_)      // 6881280
#define INV729 (1.0f / 729.0f)
#define HSEG 16
#define NSEG (H_ / HSEG)        // 12

// ---------------------------------------------------------------------------
__global__ void k_init(double* acc) { *acc = 0.0; }

// ---------------------------------------------------------------------------
// K1': fused W-sum + H-sum, register-prefetched (T14 async-stage split).
// One block per (d, h-segment). Per h-step: write the prefetched raw row into
// LDS buffer cur, issue the global load for the NEXT row (latency hides under
// this step's compute), sync once, compute 9-tap W-sums of the 5 product
// channels from LDS, slide the H-sum with a 9-deep register ring.
__global__ __launch_bounds__(256) void k_passWH(const float* __restrict__ pred,
                                                const float* __restrict__ targ,
                                                float* __restrict__ out) {
    __shared__ float bI[2][W_ + 8];
    __shared__ float bJ[2][W_ + 8];
    const int d   = blockIdx.x;
    const int h0  = blockIdx.y * HSEG;
    const int t   = threadIdx.x;
    const long dbase = (long)d * HW_;
    const int wi  = t - 4;
    const bool wv = (wi >= 0) && (wi < W_);
    const int NSTEP = 9 + HSEG;

    float q[5][9], S[5];
    #pragma unroll
    for (int c = 0; c < 5; ++c) {
        S[c] = 0.f;
        #pragma unroll
        for (int k = 0; k < 9; ++k) q[c][k] = 0.f;
    }

    // prologue: prefetch first warm-up row (h0-5) into registers
    float rI = 0.f, rJ = 0.f;
    {
        const int hh = h0 - 5;
        const bool v = wv && (hh >= 0);
        const long a = dbase + (long)hh * W_ + wi;
        rI = v ? targ[a] : 0.f;
        rJ = v ? pred[a] : 0.f;
    }

    int cur = 0;
    for (int s = 0; s < NSTEP; ++s) {
        // write prefetched row into buf[cur]
        if (t < W_ + 8) { bI[cur][t] = rI; bJ[cur][t] = rJ; }
        // prefetch next row into regs (hidden under this step's compute)
        {
            const int hh = h0 - 4 + s;
            const bool v = wv && (s + 1 < NSTEP) && (hh >= 0) && (hh < H_);
            const long a = dbase + (long)hh * W_ + wi;
            rI = v ? targ[a] : 0.f;
            rJ = v ? pred[a] : 0.f;
        }
        __syncthreads();        // buf[cur] ready for all threads

        float ws0 = 0.f, ws1 = 0.f, ws2 = 0.f, ws3 = 0.f, ws4 = 0.f;
        if (t < W_) {
            #pragma unroll
            for (int k = 0; k < 9; ++k) {
                const float a = bI[cur][t + k];
                const float b = bJ[cur][t + k];
                ws0 += a;     ws1 += b;
                ws2 += a * a; ws3 += b * b; ws4 += a * b;
            }
        }
        S[0] += ws0 - q[0][0];
        S[1] += ws1 - q[1][0];
        S[2] += ws2 - q[2][0];
        S[3] += ws3 - q[3][0];
        S[4] += ws4 - q[4][0];

        if (s >= 9 && t < W_) {
            const long o = dbase + (long)(h0 + s - 9) * W_ + t;
            out[0L * N_ + o] = S[0];
            out[1L * N_ + o] = S[1];
            out[2L * N_ + o] = S[2];
            out[3L * N_ + o] = S[3];
            out[4L * N_ + o] = S[4];
        }

        #pragma unroll
        for (int c = 0; c < 5; ++c) {
            #pragma unroll
            for (int k = 0; k < 8; ++k) q[c][k] = q[c][k + 1];
        }
        q[0][8] = ws0; q[1][8] = ws1; q[2][8] = ws2; q[3][8] = ws3; q[4][8] = ws4;

        cur ^= 1;
        // safety: reads of buf[cur] (this step, pre-sync) complete before
        // writes to buf[cur] (step s+2, post-sync(s+1)). One sync/step. OK.
    }
}

// ---------------------------------------------------------------------------
// K3: 9-tap box sum along D for all 5 channels + cc + reduction.
// grid = (HW/256, 16 segments of 10 d-outputs). Read-only on buf.
__global__ __launch_bounds__(256) void k_passD(const float* __restrict__ buf,
                                               double* __restrict__ acc) {
    const int DSEG = D_ / 16;               // 10
    const int p  = blockIdx.x * blockDim.x + threadIdx.x;   // < HW_
    const int d0 = blockIdx.y * DSEG;
    const float* base = buf + p;

    float q[5][9];
    float S[5];
    #pragma unroll
    for (int c = 0; c < 5; ++c) {
        S[c] = 0.f;
        #pragma unroll
        for (int k = 0; k < 9; ++k) {
            const int dd = d0 - 5 + k;      // d0+3 <= 153 < 160
            const float v = (dd >= 0) ? base[(long)c * N_ + (long)dd * HW_] : 0.f;
            q[c][k] = v;
            S[c] += v;
        }
    }

    float myacc = 0.f;
    #pragma unroll 2
    for (int d = d0; d < d0 + DSEG; ++d) {
        float nv[5];
        #pragma unroll
        for (int c = 0; c < 5; ++c) {
            nv[c] = (d + 4 < D_) ? base[(long)c * N_ + (long)(d + 4) * HW_] : 0.f;
            S[c] += nv[c] - q[c][0];
            #pragma unroll
            for (int k = 0; k < 8; ++k) q[c][k] = q[c][k + 1];
            q[c][8] = nv[c];
        }
        const float mu1 = S[0] * INV729;
        const float mu2 = S[1] * INV729;
        const float s1  = S[2] * INV729 - mu1 * mu1;
        const float s2  = S[3] * INV729 - mu2 * mu2;
        const float s12 = S[4] * INV729 - mu1 * mu2;
        const float den = fmaxf(s1 * s2, 1.1920929e-7f);   // finfo(f32).eps
        myacc += (s12 * s12) / den;
    }

    __shared__ float red[256];
    red[threadIdx.x] = myacc;
    __syncthreads();
    #pragma unroll
    for (int s = 128; s > 0; s >>= 1) {
        if (threadIdx.x < s) red[threadIdx.x] += red[threadIdx.x + s];
        __syncthreads();
    }
    if (threadIdx.x == 0) atomicAdd(acc, (double)red[0]);
}

// ---------------------------------------------------------------------------
__global__ void k_fin(const double* __restrict__ acc, float* __restrict__ out) {
    out[0] = (float)(-(*acc) / (double)N_);
}

// ---------------------------------------------------------------------------
extern "C" void kernel_launch(void* const* d_in, const int* in_sizes, int n_in,
                              void* d_out, int out_size, void* d_ws, size_t ws_size,
                              hipStream_t stream) {
    const float* pred = (const float*)d_in[0];
    const float* targ = (const float*)d_in[1];

    float*  buf = (float*)d_ws;                                   // 5*N floats
    double* acc = (double*)((char*)d_ws + (size_t)5 * N_ * 4);
    float*  out = (float*)d_out;

    k_init<<<1, 1, 0, stream>>>(acc);
    dim3 g1(D_, NSEG);          // 160 x 12
    k_passWH<<<g1, 256, 0, stream>>>(pred, targ, buf);
    dim3 g3(HW_ / 256, 16);     // 168 x 16
    k_passD<<<g3, 256, 0, stream>>>(buf, acc);
    k_fin<<<1, 1, 0, stream>>>(acc, out);
}

// Round 4
// 99.049 us; speedup vs baseline: 1.0673x; 1.0673x over previous
//
#include <hip/hip_runtime.h>

#define D_  160
#define H_  192
#define W_  224
#define HW_ (H_ * W_)           // 43008
#define N_  (D_ * H_ * W_)      // 6881280
#define INV729 (1.0f / 729.0f)
#define HSEG 16
#define NSEG (H_ / HSEG)        // 12
#define NSTEP2 13               // two-row steps: 26 pushed rows per block

// ---------------------------------------------------------------------------
__global__ void k_init(double* acc) { *acc = 0.0; }

// ---------------------------------------------------------------------------
// Fused W+H box-sum. Block = (d, h-segment). Each step stages TWO raw rows
// (I and J) via float4->LDS double buffer, computes 9-tap W-sums of the 5
// product channels, slides the H-sum with a statically-indexed mod-9 ring
// (whole step loop unrolled -> no ring-shift movs), emits 2 output rows.
__global__ __launch_bounds__(256, 4) void k_passWH(const float* __restrict__ pred,
                                                   const float* __restrict__ targ,
                                                   float* __restrict__ out) {
    __shared__ __attribute__((aligned(16))) float bI[2][2][232];
    __shared__ __attribute__((aligned(16))) float bJ[2][2][232];
    const int d  = blockIdx.x;
    const int h0 = blockIdx.y * HSEG;
    const int t  = threadIdx.x;
    const long dbase = (long)d * HW_;

    // staging role: t<224 -> row sr (0/1), array sa (0=I=targ,1=J=pred), chunk sc
    const int sr = t / 112;
    const int sa = (t % 112) / 56;
    const int sc = (t % 56) * 4;
    const bool stg = (t < 224);
    const float* src = sa ? pred : targ;

    // zero the w-halos once (slots [0..3] and [228..231] of every buffer row)
    if (t < 16) {
        const int cb = t & 1, r = (t >> 1) & 1, a = (t >> 2) & 1, side = (t >> 3) & 1;
        float* p = (a ? &bJ[cb][r][0] : &bI[cb][r][0]) + side * 228;
        p[0] = 0.f; p[1] = 0.f; p[2] = 0.f; p[3] = 0.f;
    }

    float q[5][9], S[5];
    #pragma unroll
    for (int c = 0; c < 5; ++c) {
        S[c] = 0.f;
        #pragma unroll
        for (int k = 0; k < 9; ++k) q[c][k] = 0.f;
    }

    // prologue prefetch: rows h0-6 (r=0), h0-5 (r=1)
    float4 pf = {0.f, 0.f, 0.f, 0.f};
    {
        const int hh = h0 - 6 + sr;
        if (stg && hh >= 0 && hh < H_)
            pf = *(const float4*)(src + dbase + (long)hh * W_ + sc);
    }

    #pragma unroll
    for (int k = 0; k < NSTEP2; ++k) {
        const int cur = k & 1;
        if (stg) {
            float* dst = sa ? &bJ[cur][sr][4 + sc] : &bI[cur][sr][4 + sc];
            *(float4*)dst = pf;
        }
        // prefetch next 2 rows (hidden under this step's compute)
        pf = {0.f, 0.f, 0.f, 0.f};
        if (stg && (k + 1 < NSTEP2)) {
            const int hh = h0 - 6 + 2 * (k + 1) + sr;
            if (hh >= 0 && hh < H_)
                pf = *(const float4*)(src + dbase + (long)hh * W_ + sc);
        }
        __syncthreads();
        // hazard note: step k reads buf[cur] after barrier(k); the next write
        // to buf[cur] is in step k+2, after barrier(k+1). One barrier/step OK.

        if (t < W_) {
            #pragma unroll
            for (int r = 0; r < 2; ++r) {
                const int p = 2 * k + r;          // compile-time
                float w0 = 0.f, w1 = 0.f, w2 = 0.f, w3 = 0.f, w4 = 0.f;
                #pragma unroll
                for (int kk = 0; kk < 9; ++kk) {
                    const float a = bI[cur][r][t + kk];
                    const float b = bJ[cur][r][t + kk];
                    w0 += a;     w1 += b;
                    w2 += a * a; w3 += b * b; w4 += a * b;
                }
                S[0] += w0 - q[0][p % 9]; q[0][p % 9] = w0;
                S[1] += w1 - q[1][p % 9]; q[1][p % 9] = w1;
                S[2] += w2 - q[2][p % 9]; q[2][p % 9] = w2;
                S[3] += w3 - q[3][p % 9]; q[3][p % 9] = w3;
                S[4] += w4 - q[4][p % 9]; q[4][p % 9] = w4;
                if (p >= 10) {                    // emit row h0-10+p
                    const long o = dbase + (long)(h0 - 10 + p) * W_ + t;
                    out[0L * N_ + o] = S[0];
                    out[1L * N_ + o] = S[1];
                    out[2L * N_ + o] = S[2];
                    out[3L * N_ + o] = S[3];
                    out[4L * N_ + o] = S[4];
                }
            }
        }
    }
}

// ---------------------------------------------------------------------------
// D-axis 9-tap sliding sum + cc + reduction. Fully unrolled, static mod-9 ring.
// grid = (HW/256, 8 segments of 20 d-outputs).
__global__ __launch_bounds__(256, 4) void k_passD(const float* __restrict__ buf,
                                                  double* __restrict__ acc) {
    const int DSEG = D_ / 8;                // 20
    const int p  = blockIdx.x * blockDim.x + threadIdx.x;   // < HW_
    const int d0 = blockIdx.y * DSEG;
    const float* base = buf + p;

    float q[5][9], S[5];
    #pragma unroll
    for (int c = 0; c < 5; ++c) {
        S[c] = 0.f;
        #pragma unroll
        for (int k = 0; k < 9; ++k) {
            const int dd = d0 - 5 + k;      // d0+3 <= 143 < 160
            const float v = (dd >= 0) ? base[(long)c * N_ + (long)dd * HW_] : 0.f;
            q[c][k] = v;
            S[c] += v;
        }
    }

    float myacc = 0.f;
    #pragma unroll
    for (int j = 0; j < DSEG; ++j) {        // output d = d0+j
        const int dd = d0 + 4 + j;
        #pragma unroll
        for (int c = 0; c < 5; ++c) {
            const float nv = (dd < D_) ? base[(long)c * N_ + (long)dd * HW_] : 0.f;
            S[c] += nv - q[c][j % 9];
            q[c][j % 9] = nv;
        }
        const float mu1 = S[0] * INV729;
        const float mu2 = S[1] * INV729;
        const float s1  = S[2] * INV729 - mu1 * mu1;
        const float s2  = S[3] * INV729 - mu2 * mu2;
        const float s12 = S[4] * INV729 - mu1 * mu2;
        const float den = fmaxf(s1 * s2, 1.1920929e-7f);   // finfo(f32).eps
        myacc += (s12 * s12) * __builtin_amdgcn_rcpf(den);
    }

    __shared__ float red[256];
    red[threadIdx.x] = myacc;
    __syncthreads();
    #pragma unroll
    for (int s = 128; s > 0; s >>= 1) {
        if (threadIdx.x < s) red[threadIdx.x] += red[threadIdx.x + s];
        __syncthreads();
    }
    if (threadIdx.x == 0) atomicAdd(acc, (double)red[0]);
}

// ---------------------------------------------------------------------------
__global__ void k_fin(const double* __restrict__ acc, float* __restrict__ out) {
    out[0] = (float)(-(*acc) / (double)N_);
}

// ---------------------------------------------------------------------------
extern "C" void kernel_launch(void* const* d_in, const int* in_sizes, int n_in,
                              void* d_out, int out_size, void* d_ws, size_t ws_size,
                              hipStream_t stream) {
    const float* pred = (const float*)d_in[0];
    const float* targ = (const float*)d_in[1];

    float*  buf = (float*)d_ws;                                   // 5*N floats
    double* acc = (double*)((char*)d_ws + (size_t)5 * N_ * 4);
    float*  out = (float*)d_out;

    k_init<<<1, 1, 0, stream>>>(acc);
    dim3 g1(D_, NSEG);          // 160 x 12
    k_passWH<<<g1, 256, 0, stream>>>(pred, targ, buf);
    dim3 g3(HW_ / 256, 8);      // 168 x 8
    k_passD<<<g3, 256, 0, stream>>>(buf, acc);
    k_fin<<<1, 1, 0, stream>>>(acc, out);
}